// Round 7
// baseline (272.841 us; speedup 1.0000x reference)
//
#include <hip/hip_runtime.h>
#include <math.h>

// Problem constants (fixed by the reference)
#define N_TOT 200000
#define D_    32
#define MK    1024          // M*K = 64*16
#define EPS_DIV  1e-29f

// Work decomposition: each WAVE owns COLS mk-columns and streams ROWS-row n-tiles.
#define ROWS  16            // n rows per wave-task (one MFMA tile height)
#define COLS  128           // mk cols per wave = NT tiles of 16
#define NT    8             // 16-col tiles per wave
#define NMKE  (MK / COLS)   // 8 column-slices
#define NTILE (N_TOT / ROWS)// 12500 n-tiles
#define NBLK  4096          // blocks (x4 waves = 16384 waves; 2048 per slice)
#define WQ    ((NBLK * 4) / NMKE)   // 2048 waves per column-slice

typedef __attribute__((ext_vector_type(8))) short short8;
typedef __attribute__((ext_vector_type(4))) float f32x4;

__device__ __forceinline__ unsigned short f2bf(float x) {
    unsigned int u = __float_as_uint(x);
    u += 0x7FFFu + ((u >> 16) & 1u);          // round-to-nearest-even
    return (unsigned short)(u >> 16);
}
__device__ __forceinline__ float bf2f(unsigned short h) {
    return __uint_as_float(((unsigned int)h) << 16);
}

// ---------------------------------------------------------------------------
// Prep: softmax(alpha) folded with affine epilogue, split into bf16 hi/lo.
//   W[mk][d] = softmax(alpha[mk])[d] / (pos-neg+eps)   -> Whi + Wlo (bf16)
//   off[mk]  = (-th-neg)/(pos-neg+eps)
// Then B = clip( T·W + off, 0, 1 ).
// (The reference's |temp|<1e-5 zeroing changes the output by <= 1e-5/(pos-neg)
//  ~ 5e-5, far below the 2e-2 tolerance -> folded away entirely.)
// ---------------------------------------------------------------------------
__global__ __launch_bounds__(256) void prep_kernel(
    const float* __restrict__ alpha, const float* __restrict__ th,
    const float* __restrict__ amb,
    unsigned short* __restrict__ Whi, unsigned short* __restrict__ Wlo,
    float* __restrict__ off)
{
    int mk = blockIdx.x * 256 + threadIdx.x;
    if (mk >= MK) return;
    float v[D_];
    float mx = -1e30f;
#pragma unroll
    for (int d = 0; d < D_; ++d) { v[d] = alpha[mk * D_ + d]; mx = fmaxf(mx, v[d]); }
    float sum = 0.f;
#pragma unroll
    for (int d = 0; d < D_; ++d) { v[d] = expf(v[d] - mx); sum += v[d]; }
    float pos = amb[mk * 2 + 0];
    float neg = amb[mk * 2 + 1];
    float s  = 1.0f / (pos - neg + EPS_DIV);
    float si = s / sum;
#pragma unroll
    for (int d = 0; d < D_; ++d) {
        float w = v[d] * si;
        unsigned short h = f2bf(w);
        Whi[mk * D_ + d] = h;
        Wlo[mk * D_ + d] = f2bf(w - bf2f(h));
    }
    off[mk] = (0.0f - th[mk] - neg) * s;
}

// ---------------------------------------------------------------------------
// Main: zero-LDS, zero-barrier streaming MFMA kernel, SWAPPED operands:
//   D = A(=W slice, 16 mk-rows) x B(=T tile, 16 n-cols)
// so each lane's 4 acc elements are 4 CONSECUTIVE mk columns of one output
// row -> float4 nontemporal stores (16 B/lane, 1 store instr per 16x16 tile).
// W fragments + off vectors hoisted into registers once per wave.
// 3-MFMA hi/lo split keeps fp32-level accuracy (Tlo*Wlo term dropped).
// ---------------------------------------------------------------------------
__global__ __launch_bounds__(256, 3) void fern_mfma(
    const float* __restrict__ T,
    const unsigned short* __restrict__ Whi, const unsigned short* __restrict__ Wlo,
    const float* __restrict__ off, float* __restrict__ out)
{
    const int tid     = threadIdx.x;
    const int lane    = tid & 63;
    const int wid     = tid >> 6;
    const int wave_id = blockIdx.x * 4 + wid;
    const int mke     = wave_id & (NMKE - 1);   // which 128-col slice
    const int wq      = wave_id >> 3;           // index among waves of this slice
    const int lc      = lane & 15;              // A row (mk) / B col (n) / C col (n)
    const int lk      = lane >> 4;              // k-group (8 contiguous k)
    const int mk0     = mke * COLS;

    // ---- hoist W fragments + epilogue offsets for this wave's 128 cols
    short8 wh[NT], wl[NT];
    f32x4 ofv[NT];
#pragma unroll
    for (int t = 0; t < NT; ++t) {
        long c = (long)(mk0 + t * 16 + lc);
        wh[t]  = *(const short8*)(Whi + c * D_ + lk * 8);
        wl[t]  = *(const short8*)(Wlo + c * D_ + lk * 8);
        ofv[t] = *(const f32x4*)(off + mk0 + t * 16 + lk * 4);
    }

    // ---- stream n-tiles
    for (int tile = wq; tile < NTILE; tile += WQ) {
        const int n0 = tile * ROWS;

        // T fragment (B operand): col n = n0+lc, k = lk*8 .. +7  (32 B of f32)
        const float* tp = T + (long)(n0 + lc) * D_ + lk * 8;
        float4 v0 = *(const float4*)tp;
        float4 v1 = *(const float4*)(tp + 4);
        float xs[8] = { v0.x, v0.y, v0.z, v0.w, v1.x, v1.y, v1.z, v1.w };
        short8 ah, al;
#pragma unroll
        for (int j = 0; j < 8; ++j) {
            unsigned short h = f2bf(xs[j]);
            ah[j] = (short)h;
            al[j] = (short)f2bf(xs[j] - bf2f(h));
        }

        // D[mk][n]: C col = lane&15 -> n = n0+lc ; C row = lk*4+j -> mk offset.
        // Lane stores out[n0+lc][mk0 + t*16 + lk*4 .. +3] -> float4, nt.
        float* pb = out + (long)(n0 + lc) * MK + mk0 + lk * 4;

#pragma unroll
        for (int t = 0; t < NT; ++t) {
            f32x4 acc = { 0.f, 0.f, 0.f, 0.f };
            acc = __builtin_amdgcn_mfma_f32_16x16x32_bf16(wh[t], ah, acc, 0, 0, 0);
            acc = __builtin_amdgcn_mfma_f32_16x16x32_bf16(wh[t], al, acc, 0, 0, 0);
            acc = __builtin_amdgcn_mfma_f32_16x16x32_bf16(wl[t], ah, acc, 0, 0, 0);

            f32x4 r;
#pragma unroll
            for (int j = 0; j < 4; ++j)
                r[j] = fminf(fmaxf(acc[j] + ofv[t][j], 0.f), 1.f);
            __builtin_nontemporal_store(r, (f32x4*)(pb + t * 16));
        }
    }
}

extern "C" void kernel_launch(void* const* d_in, const int* in_sizes, int n_in,
                              void* d_out, int out_size, void* d_ws, size_t ws_size,
                              hipStream_t stream)
{
    const float* T     = (const float*)d_in[0];
    const float* alpha = (const float*)d_in[1];
    const float* th    = (const float*)d_in[2];
    const float* amb   = (const float*)d_in[3];
    float* out = (float*)d_out;

    // ws layout: Whi[32768 u16] | Wlo[32768 u16] | off[1024 f32] = 135,168 B
    unsigned short* Whi = (unsigned short*)d_ws;
    unsigned short* Wlo = Whi + MK * D_;
    float* offp = (float*)(Wlo + MK * D_);

    prep_kernel<<<MK / 256, 256, 0, stream>>>(alpha, th, amb, Whi, Wlo, offp);
    fern_mfma<<<NBLK, 256, 0, stream>>>(T, Whi, Wlo, offp, out);
}

// Round 8
// 228.641 us; speedup vs baseline: 1.1933x; 1.1933x over previous
//
#include <hip/hip_runtime.h>
#include <math.h>

// Problem constants (fixed by the reference)
#define N_TOT 200000
#define D_    32
#define MK    1024          // M*K = 64*16
#define EPS_DIV  1e-29f

// Work decomposition: each WAVE owns COLS mk-columns and streams ROWS-row n-tiles.
#define ROWS  16            // n rows per wave-task (one MFMA tile height)
#define COLS  128           // mk cols per wave = NT tiles of 16
#define NT    8             // 16-col tiles per wave
#define NMKE  (MK / COLS)   // 8 column-slices
#define NTILE (N_TOT / ROWS)// 12500 n-tiles
#define NBLK  4096          // blocks (x4 waves = 16384 waves; 2048 per slice)
#define WQ    ((NBLK * 4) / NMKE)   // 2048 waves per column-slice

typedef __attribute__((ext_vector_type(8))) short short8;
typedef __attribute__((ext_vector_type(4))) float f32x4;

__device__ __forceinline__ unsigned short f2bf(float x) {
    unsigned int u = __float_as_uint(x);
    u += 0x7FFFu + ((u >> 16) & 1u);          // round-to-nearest-even
    return (unsigned short)(u >> 16);
}
__device__ __forceinline__ float bf2f(unsigned short h) {
    return __uint_as_float(((unsigned int)h) << 16);
}

// ---------------------------------------------------------------------------
// Prep: softmax(alpha) folded with affine epilogue, split into bf16 hi/lo.
//   W[mk][d] = softmax(alpha[mk])[d] / (pos-neg+eps)   -> Whi + Wlo (bf16)
//   off[mk]  = (-th-neg)/(pos-neg+eps)
// Then B = clip( T·W + off, 0, 1 ).
// (The reference's |temp|<1e-5 zeroing changes the output by <= ~5e-5,
//  far below the 2e-2 tolerance -> folded away. Validated R7: absmax
//  unchanged at the 0.0039 harness comparison floor.)
// ---------------------------------------------------------------------------
__global__ __launch_bounds__(256) void prep_kernel(
    const float* __restrict__ alpha, const float* __restrict__ th,
    const float* __restrict__ amb,
    unsigned short* __restrict__ Whi, unsigned short* __restrict__ Wlo,
    float* __restrict__ off)
{
    int mk = blockIdx.x * 256 + threadIdx.x;
    if (mk >= MK) return;
    float v[D_];
    float mx = -1e30f;
#pragma unroll
    for (int d = 0; d < D_; ++d) { v[d] = alpha[mk * D_ + d]; mx = fmaxf(mx, v[d]); }
    float sum = 0.f;
#pragma unroll
    for (int d = 0; d < D_; ++d) { v[d] = expf(v[d] - mx); sum += v[d]; }
    float pos = amb[mk * 2 + 0];
    float neg = amb[mk * 2 + 1];
    float s  = 1.0f / (pos - neg + EPS_DIV);
    float si = s / sum;
#pragma unroll
    for (int d = 0; d < D_; ++d) {
        float w = v[d] * si;
        unsigned short h = f2bf(w);
        Whi[mk * D_ + d] = h;
        Wlo[mk * D_ + d] = f2bf(w - bf2f(h));
    }
    off[mk] = (0.0f - th[mk] - neg) * s;
}

// ---------------------------------------------------------------------------
// Main: zero-LDS, zero-barrier streaming MFMA kernel, SWAPPED operands:
//   D = A(=W slice, 16 mk-rows) x B(=T tile, 16 n-cols)
// so each lane's 4 acc elements are 4 CONSECUTIVE mk columns of one output
// row -> plain float4 stores (NOT nontemporal: the nt flag defeats L2
// write-combining of our 64B segments and cost +75us in R7).
// W fragments + off vectors hoisted into registers once per wave.
// 3-MFMA hi/lo split keeps fp32-level accuracy (Tlo*Wlo term dropped).
// ---------------------------------------------------------------------------
__global__ __launch_bounds__(256, 3) void fern_mfma(
    const float* __restrict__ T,
    const unsigned short* __restrict__ Whi, const unsigned short* __restrict__ Wlo,
    const float* __restrict__ off, float* __restrict__ out)
{
    const int tid     = threadIdx.x;
    const int lane    = tid & 63;
    const int wid     = tid >> 6;
    const int wave_id = blockIdx.x * 4 + wid;
    const int mke     = wave_id & (NMKE - 1);   // which 128-col slice
    const int wq      = wave_id >> 3;           // index among waves of this slice
    const int lc      = lane & 15;              // A row (mk) / B col (n) / C col (n)
    const int lk      = lane >> 4;              // k-group (8 contiguous k)
    const int mk0     = mke * COLS;

    // ---- hoist W fragments + epilogue offsets for this wave's 128 cols
    short8 wh[NT], wl[NT];
    f32x4 ofv[NT];
#pragma unroll
    for (int t = 0; t < NT; ++t) {
        long c = (long)(mk0 + t * 16 + lc);
        wh[t]  = *(const short8*)(Whi + c * D_ + lk * 8);
        wl[t]  = *(const short8*)(Wlo + c * D_ + lk * 8);
        ofv[t] = *(const f32x4*)(off + mk0 + t * 16 + lk * 4);
    }

    // ---- stream n-tiles
    for (int tile = wq; tile < NTILE; tile += WQ) {
        const int n0 = tile * ROWS;

        // T fragment (B operand): col n = n0+lc, k = lk*8 .. +7  (32 B of f32)
        const float* tp = T + (long)(n0 + lc) * D_ + lk * 8;
        float4 v0 = *(const float4*)tp;
        float4 v1 = *(const float4*)(tp + 4);
        float xs[8] = { v0.x, v0.y, v0.z, v0.w, v1.x, v1.y, v1.z, v1.w };
        short8 ah, al;
#pragma unroll
        for (int j = 0; j < 8; ++j) {
            unsigned short h = f2bf(xs[j]);
            ah[j] = (short)h;
            al[j] = (short)f2bf(xs[j] - bf2f(h));
        }

        // D[mk][n] swapped: C col = lane&15 -> n = n0+lc ; C "row" = lk*4+j -> mk.
        // Lane stores out[n0+lc][mk0 + t*16 + lk*4 .. +3] -> one float4 per tile.
        float* pb = out + (long)(n0 + lc) * MK + mk0 + lk * 4;

#pragma unroll
        for (int t = 0; t < NT; ++t) {
            f32x4 acc = { 0.f, 0.f, 0.f, 0.f };
            acc = __builtin_amdgcn_mfma_f32_16x16x32_bf16(wh[t], ah, acc, 0, 0, 0);
            acc = __builtin_amdgcn_mfma_f32_16x16x32_bf16(wh[t], al, acc, 0, 0, 0);
            acc = __builtin_amdgcn_mfma_f32_16x16x32_bf16(wl[t], ah, acc, 0, 0, 0);

            f32x4 r;
#pragma unroll
            for (int j = 0; j < 4; ++j)
                r[j] = fminf(fmaxf(acc[j] + ofv[t][j], 0.f), 1.f);
            *(f32x4*)(pb + t * 16) = r;
        }
    }
}

extern "C" void kernel_launch(void* const* d_in, const int* in_sizes, int n_in,
                              void* d_out, int out_size, void* d_ws, size_t ws_size,
                              hipStream_t stream)
{
    const float* T     = (const float*)d_in[0];
    const float* alpha = (const float*)d_in[1];
    const float* th    = (const float*)d_in[2];
    const float* amb   = (const float*)d_in[3];
    float* out = (float*)d_out;

    // ws layout: Whi[32768 u16] | Wlo[32768 u16] | off[1024 f32] = 135,168 B
    unsigned short* Whi = (unsigned short*)d_ws;
    unsigned short* Wlo = Whi + MK * D_;
    float* offp = (float*)(Wlo + MK * D_);

    prep_kernel<<<MK / 256, 256, 0, stream>>>(alpha, th, amb, Whi, Wlo, offp);
    fern_mfma<<<NBLK, 256, 0, stream>>>(T, Whi, Wlo, offp, out);
}

// Round 9
// 207.677 us; speedup vs baseline: 1.3138x; 1.1009x over previous
//
#include <hip/hip_runtime.h>
#include <math.h>

// Problem constants (fixed by the reference)
#define N_TOT 200000
#define D_    32
#define MK    1024          // M*K = 64*16
#define EPS_ZERO 1e-5f
#define EPS_DIV  1e-29f

// Work decomposition: each WAVE owns COLS mk-columns and streams ROWS-row n-tiles.
#define ROWS  16            // n rows per wave-task (one MFMA tile height)
#define COLS  128           // mk cols per wave = NT tiles of 16
#define NT    8             // 16-col tiles per wave
#define NMKE  (MK / COLS)   // 8 column-slices
#define NTILE (N_TOT / ROWS)// 12500 n-tiles
#define NBLK  4096          // blocks (x4 waves = 16384 waves; 2048 per slice)
#define WQ    ((NBLK * 4) / NMKE)   // 2048 waves per column-slice

typedef __attribute__((ext_vector_type(8))) short short8;
typedef __attribute__((ext_vector_type(4))) float f32x4;

__device__ __forceinline__ unsigned short f2bf(float x) {
    unsigned int u = __float_as_uint(x);
    u += 0x7FFFu + ((u >> 16) & 1u);          // round-to-nearest-even
    return (unsigned short)(u >> 16);
}
__device__ __forceinline__ float bf2f(unsigned short h) {
    return __uint_as_float(((unsigned int)h) << 16);
}

// ---------------------------------------------------------------------------
// Prep: softmax(alpha) folded with affine epilogue, split into bf16 hi/lo.
//   W[mk][d] = softmax(alpha[mk])[d] / (pos-neg+eps)   -> Whi + Wlo (bf16)
//   ot[mk]   = { (-th-neg)/(pos-neg+eps),  EPS_ZERO/(pos-neg+eps) }
// Then B = clip( |acc| < thr ? off : acc + off, 0, 1 ),  acc = T·W
// ---------------------------------------------------------------------------
__global__ __launch_bounds__(256) void prep_kernel(
    const float* __restrict__ alpha, const float* __restrict__ th,
    const float* __restrict__ amb,
    unsigned short* __restrict__ Whi, unsigned short* __restrict__ Wlo,
    float* __restrict__ ot)
{
    int mk = blockIdx.x * 256 + threadIdx.x;
    if (mk >= MK) return;
    float v[D_];
    float mx = -1e30f;
#pragma unroll
    for (int d = 0; d < D_; ++d) { v[d] = alpha[mk * D_ + d]; mx = fmaxf(mx, v[d]); }
    float sum = 0.f;
#pragma unroll
    for (int d = 0; d < D_; ++d) { v[d] = expf(v[d] - mx); sum += v[d]; }
    float pos = amb[mk * 2 + 0];
    float neg = amb[mk * 2 + 1];
    float s  = 1.0f / (pos - neg + EPS_DIV);
    float si = s / sum;
#pragma unroll
    for (int d = 0; d < D_; ++d) {
        float w = v[d] * si;
        unsigned short h = f2bf(w);
        Whi[mk * D_ + d] = h;
        Wlo[mk * D_ + d] = f2bf(w - bf2f(h));
    }
    ot[2 * mk + 0] = (0.0f - th[mk] - neg) * s;
    ot[2 * mk + 1] = EPS_ZERO * s;
}

// ---------------------------------------------------------------------------
// Main: zero-LDS, zero-barrier streaming MFMA kernel (R6 structure) plus a
// register double-buffer on the T fragment: next tile's 2x dwordx4 loads are
// issued BEFORE the current tile's convert/MFMA/store burst, so their latency
// hides under 24 MFMAs + 32 stores (Guideline 7). Everything else == R6.
// 3-MFMA hi/lo split keeps fp32-level accuracy (Tlo*Wlo term dropped).
// ---------------------------------------------------------------------------
__global__ __launch_bounds__(256, 3) void fern_mfma(
    const float* __restrict__ T,
    const unsigned short* __restrict__ Whi, const unsigned short* __restrict__ Wlo,
    const float* __restrict__ ot, float* __restrict__ out)
{
    const int tid     = threadIdx.x;
    const int lane    = tid & 63;
    const int wid     = tid >> 6;
    const int wave_id = blockIdx.x * 4 + wid;
    const int mke     = wave_id & (NMKE - 1);   // which 128-col slice
    const int wq      = wave_id >> 3;           // index among waves of this slice
    const int lc      = lane & 15;              // A row / B col / C col
    const int lk      = lane >> 4;              // k-group (8 contiguous k)
    const int mk0     = mke * COLS;

    // ---- hoist W fragments + epilogue constants for this wave's 128 cols
    short8 wh[NT], wl[NT];
    float2 o2[NT];
#pragma unroll
    for (int t = 0; t < NT; ++t) {
        long c = (long)(mk0 + t * 16 + lc);
        wh[t] = *(const short8*)(Whi + c * D_ + lk * 8);
        wl[t] = *(const short8*)(Wlo + c * D_ + lk * 8);
        o2[t] = *(const float2*)(ot + 2 * c);
    }

    // ---- prologue: load first T fragment (row n0+lc, k = lk*8..+7)
    const long lrow = (long)lc * D_ + lk * 8;   // lane-constant part of T offset
    float4 c0, c1;
    {
        const float* tp = T + (long)(wq * ROWS) * D_ + lrow;
        c0 = *(const float4*)tp;
        c1 = *(const float4*)(tp + 4);
    }

    // ---- stream n-tiles
    for (int tile = wq; tile < NTILE; tile += WQ) {
        const int n0 = tile * ROWS;

        // prefetch NEXT tile's T fragment (clamped; uniform, no divergence)
        int nxt = tile + WQ;
        if (nxt >= NTILE) nxt = tile;
        const float* tpn = T + (long)(nxt * ROWS) * D_ + lrow;
        float4 p0 = *(const float4*)tpn;
        float4 p1 = *(const float4*)(tpn + 4);

        // convert CURRENT T fragment to bf16 hi/lo
        float xs[8] = { c0.x, c0.y, c0.z, c0.w, c1.x, c1.y, c1.z, c1.w };
        short8 ah, al;
#pragma unroll
        for (int j = 0; j < 8; ++j) {
            unsigned short h = f2bf(xs[j]);
            ah[j] = (short)h;
            al[j] = (short)f2bf(xs[j] - bf2f(h));
        }

        // C/D layout: col = lane&15, row = (lane>>4)*4 + j  [measured m89/m91]
        float* r0 = out + ((long)(n0 + lk * 4 + 0)) * MK + mk0 + lc;
        float* r1 = r0 + MK;
        float* r2 = r1 + MK;
        float* r3 = r2 + MK;

#pragma unroll
        for (int t = 0; t < NT; ++t) {
            f32x4 acc = { 0.f, 0.f, 0.f, 0.f };
            acc = __builtin_amdgcn_mfma_f32_16x16x32_bf16(ah, wh[t], acc, 0, 0, 0);
            acc = __builtin_amdgcn_mfma_f32_16x16x32_bf16(al, wh[t], acc, 0, 0, 0);
            acc = __builtin_amdgcn_mfma_f32_16x16x32_bf16(ah, wl[t], acc, 0, 0, 0);

            const float off = o2[t].x, thr = o2[t].y;
            float x0 = acc[0], x1 = acc[1], x2 = acc[2], x3 = acc[3];
            x0 = (fabsf(x0) < thr) ? off : (x0 + off);
            x1 = (fabsf(x1) < thr) ? off : (x1 + off);
            x2 = (fabsf(x2) < thr) ? off : (x2 + off);
            x3 = (fabsf(x3) < thr) ? off : (x3 + off);
            r0[t * 16] = fminf(fmaxf(x0, 0.f), 1.f);
            r1[t * 16] = fminf(fmaxf(x1, 0.f), 1.f);
            r2[t * 16] = fminf(fmaxf(x2, 0.f), 1.f);
            r3[t * 16] = fminf(fmaxf(x3, 0.f), 1.f);
        }

        c0 = p0; c1 = p1;
    }
}

extern "C" void kernel_launch(void* const* d_in, const int* in_sizes, int n_in,
                              void* d_out, int out_size, void* d_ws, size_t ws_size,
                              hipStream_t stream)
{
    const float* T     = (const float*)d_in[0];
    const float* alpha = (const float*)d_in[1];
    const float* th    = (const float*)d_in[2];
    const float* amb   = (const float*)d_in[3];
    float* out = (float*)d_out;

    // ws layout: Whi[32768 u16] | Wlo[32768 u16] | ot[1024 float2]  = 139,264 B
    unsigned short* Whi = (unsigned short*)d_ws;
    unsigned short* Wlo = Whi + MK * D_;
    float* ot = (float*)(Wlo + MK * D_);

    prep_kernel<<<MK / 256, 256, 0, stream>>>(alpha, th, amb, Whi, Wlo, ot);
    fern_mfma<<<NBLK, 256, 0, stream>>>(T, Whi, Wlo, ot, out);
}

// Round 10
// 189.685 us; speedup vs baseline: 1.4384x; 1.0949x over previous
//
#include <hip/hip_runtime.h>
#include <math.h>

// Problem constants (fixed by the reference)
#define N_TOT 200000
#define D_    32
#define MK    1024          // M*K = 64*16
#define EPS_DIV  1e-29f

// Work decomposition: each WAVE owns COLS mk-columns and streams ROWS-row n-tiles.
#define ROWS  16            // n rows per wave-task (one MFMA tile height)
#define COLS  128           // mk cols per wave = NT tiles of 16
#define NT    8             // 16-col tiles per wave
#define NMKE  (MK / COLS)   // 8 column-slices
#define NTILE (N_TOT / ROWS)// 12500 n-tiles
#define NBLK  4096          // blocks (x4 waves = 16384 waves; 2048 per slice)
#define WQ    ((NBLK * 4) / NMKE)   // 2048 waves per column-slice
#define LDSW  132           // padded row stride (floats) for the stage tile

typedef __attribute__((ext_vector_type(8))) short short8;
typedef __attribute__((ext_vector_type(4))) float f32x4;

__device__ __forceinline__ unsigned short f2bf(float x) {
    unsigned int u = __float_as_uint(x);
    u += 0x7FFFu + ((u >> 16) & 1u);          // round-to-nearest-even
    return (unsigned short)(u >> 16);
}
__device__ __forceinline__ float bf2f(unsigned short h) {
    return __uint_as_float(((unsigned int)h) << 16);
}

// ---------------------------------------------------------------------------
// Prep: softmax(alpha) folded with affine epilogue, split into bf16 hi/lo.
//   W[mk][d] = softmax(alpha[mk])[d] / (pos-neg+eps)   -> Whi + Wlo (bf16)
//   off[mk]  = (-th-neg)/(pos-neg+eps)
// Then B = clip( T·W + off, 0, 1 ).  (|temp|<1e-5 zeroing folded away:
// <= ~5e-5 output delta, validated in R7/R8 — absmax unchanged at floor.)
// ---------------------------------------------------------------------------
__global__ __launch_bounds__(256) void prep_kernel(
    const float* __restrict__ alpha, const float* __restrict__ th,
    const float* __restrict__ amb,
    unsigned short* __restrict__ Whi, unsigned short* __restrict__ Wlo,
    float* __restrict__ off)
{
    int mk = blockIdx.x * 256 + threadIdx.x;
    if (mk >= MK) return;
    float v[D_];
    float mx = -1e30f;
#pragma unroll
    for (int d = 0; d < D_; ++d) { v[d] = alpha[mk * D_ + d]; mx = fmaxf(mx, v[d]); }
    float sum = 0.f;
#pragma unroll
    for (int d = 0; d < D_; ++d) { v[d] = expf(v[d] - mx); sum += v[d]; }
    float pos = amb[mk * 2 + 0];
    float neg = amb[mk * 2 + 1];
    float s  = 1.0f / (pos - neg + EPS_DIV);
    float si = s / sum;
#pragma unroll
    for (int d = 0; d < D_; ++d) {
        float w = v[d] * si;
        unsigned short h = f2bf(w);
        Whi[mk * D_ + d] = h;
        Wlo[mk * D_ + d] = f2bf(w - bf2f(h));
    }
    off[mk] = (0.0f - th[mk] - neg) * s;
}

// ---------------------------------------------------------------------------
// Main: zero-barrier streaming MFMA with LDS-GATHERED CONTIGUOUS STORES.
// Swapped operands (R8-verified mapping): D tile = [16 mk][16 n] per t, so a
// lane's f32x4 acc is 4 CONSECUTIVE mk of one n-row -> 1 ds_write_b128/tile
// into a per-wave private LDS stage [16 n-rows][128 mk + pad]. Readback is
// row-linear: 8x { ds_read_b128 + epilogue + global_store_dwordx4 }, each
// store instruction covering 2 rows x 512 B CONTIGUOUS (fill-kernel shape),
// vs the 4x64B scattered segments of R5/R6/R9 (~4.1 TB/s wall).
// No __syncthreads anywhere: LDS chunks are wave-private (lgkmcnt ordering).
// 3-MFMA hi/lo split keeps fp32-level accuracy (Tlo*Wlo term dropped).
// ---------------------------------------------------------------------------
__global__ __launch_bounds__(256, 4) void fern_mfma(
    const float* __restrict__ T,
    const unsigned short* __restrict__ Whi, const unsigned short* __restrict__ Wlo,
    const float* __restrict__ off, float* __restrict__ out)
{
    __shared__ float stage[4][ROWS][LDSW];      // 4 waves x 8448 B = 33792 B

    const int tid     = threadIdx.x;
    const int lane    = tid & 63;
    const int wid     = tid >> 6;
    const int wave_id = blockIdx.x * 4 + wid;
    const int mke     = wave_id & (NMKE - 1);   // which 128-col slice
    const int wq      = wave_id >> 3;           // index among waves of this slice
    const int lc      = lane & 15;              // A row (mk) / B col (n)
    const int lk      = lane >> 4;              // k-group (8 contiguous k)
    const int il      = lane & 31;              // store-phase column lane
    const int mk0     = mke * COLS;

    // ---- hoist W fragments (A operand, swapped) for this wave's 128 cols
    short8 wh[NT], wl[NT];
#pragma unroll
    for (int t = 0; t < NT; ++t) {
        long c = (long)(mk0 + t * 16 + lc);
        wh[t] = *(const short8*)(Whi + c * D_ + lk * 8);
        wl[t] = *(const short8*)(Wlo + c * D_ + lk * 8);
    }
    // ---- hoist store-phase epilogue constants: cols mk0 + 4*il .. +3
    const f32x4 ofv = *(const f32x4*)(off + mk0 + 4 * il);

    float* sw = &stage[wid][lc][0];             // MFMA-side write base (row lc)

    // ---- stream n-tiles
    for (int tile = wq; tile < NTILE; tile += WQ) {
        const int n0 = tile * ROWS;

        // T fragment (B operand): col n = n0+lc, k = lk*8 .. +7  (32 B of f32)
        const float* tp = T + (long)(n0 + lc) * D_ + lk * 8;
        float4 v0 = *(const float4*)tp;
        float4 v1 = *(const float4*)(tp + 4);
        float xs[8] = { v0.x, v0.y, v0.z, v0.w, v1.x, v1.y, v1.z, v1.w };
        short8 ah, al;
#pragma unroll
        for (int j = 0; j < 8; ++j) {
            unsigned short h = f2bf(xs[j]);
            ah[j] = (short)h;
            al[j] = (short)f2bf(xs[j] - bf2f(h));
        }

        // ---- compute 8 tiles; stage raw acc into LDS (1 b128 write per tile)
        // D[mk][n] swapped: n-row = lc, mk cols = t*16 + lk*4 + (0..3)  [R8-verified]
#pragma unroll
        for (int t = 0; t < NT; ++t) {
            f32x4 acc = { 0.f, 0.f, 0.f, 0.f };
            acc = __builtin_amdgcn_mfma_f32_16x16x32_bf16(wh[t], ah, acc, 0, 0, 0);
            acc = __builtin_amdgcn_mfma_f32_16x16x32_bf16(wh[t], al, acc, 0, 0, 0);
            acc = __builtin_amdgcn_mfma_f32_16x16x32_bf16(wl[t], ah, acc, 0, 0, 0);
            *(f32x4*)(sw + t * 16 + lk * 4) = acc;
        }

        // ---- readback row-linear + epilogue + contiguous stores
        // store s: lanes 0-31 -> row 2s, lanes 32-63 -> row 2s+1; col = 4*il.
        // Each instruction writes 2 x 512 B contiguous runs.
#pragma unroll
        for (int s = 0; s < 8; ++s) {
            const int r = 2 * s + (lane >> 5);
            f32x4 v = *(const f32x4*)(&stage[wid][r][4 * il]);
            f32x4 rr;
#pragma unroll
            for (int j = 0; j < 4; ++j)
                rr[j] = fminf(fmaxf(v[j] + ofv[j], 0.f), 1.f);
            *(f32x4*)(out + (long)(n0 + r) * MK + mk0 + 4 * il) = rr;
        }
    }
}

extern "C" void kernel_launch(void* const* d_in, const int* in_sizes, int n_in,
                              void* d_out, int out_size, void* d_ws, size_t ws_size,
                              hipStream_t stream)
{
    const float* T     = (const float*)d_in[0];
    const float* alpha = (const float*)d_in[1];
    const float* th    = (const float*)d_in[2];
    const float* amb   = (const float*)d_in[3];
    float* out = (float*)d_out;

    // ws layout: Whi[32768 u16] | Wlo[32768 u16] | off[1024 f32] = 135,168 B
    unsigned short* Whi = (unsigned short*)d_ws;
    unsigned short* Wlo = Whi + MK * D_;
    float* offp = (float*)(Wlo + MK * D_);

    prep_kernel<<<MK / 256, 256, 0, stream>>>(alpha, th, amb, Whi, Wlo, offp);
    fern_mfma<<<NBLK, 256, 0, stream>>>(T, Whi, Wlo, offp, out);
}

// Round 11
// 167.524 us; speedup vs baseline: 1.6287x; 1.1323x over previous
//
#include <hip/hip_runtime.h>
#include <math.h>

// Problem constants (fixed by the reference)
#define N_TOT 200000
#define D_    32
#define MK    1024          // M*K = 64*16
#define EPS_DIV  1e-29f

// Decomposition: BLOCK = 16-row strip x 512-col half; 4 waves own 4 adjacent
// 128-col slices; cooperative row-linear store of the half-strip.
#define ROWS   16
#define HALF   512          // cols per block
#define NT     8            // 16-col MFMA tiles per wave (128 cols)
#define NSTRIP (N_TOT / ROWS)        // 12500
#define NTASK  (NSTRIP * 2)          // 25000 (strip, half) tasks
#define NBLK   4096         // even: task&1 == blockIdx&1 (half fixed per block)
#define LDSF   512          // stage row stride in f32 (no pad; XOR swizzle)

typedef __attribute__((ext_vector_type(8))) short short8;
typedef __attribute__((ext_vector_type(4))) float f32x4;

__device__ __forceinline__ unsigned short f2bf(float x) {
    unsigned int u = __float_as_uint(x);
    u += 0x7FFFu + ((u >> 16) & 1u);          // round-to-nearest-even
    return (unsigned short)(u >> 16);
}
__device__ __forceinline__ float bf2f(unsigned short h) {
    return __uint_as_float(((unsigned int)h) << 16);
}

// ---------------------------------------------------------------------------
// Prep: softmax(alpha) folded with affine epilogue, split into bf16 hi/lo.
//   W[mk][d] = softmax(alpha[mk])[d] / (pos-neg+eps)   -> Whi + Wlo (bf16)
//   off[mk]  = (-th-neg)/(pos-neg+eps)
// Then B = clip( T·W + off, 0, 1 ).  (|temp|<1e-5 zeroing folded away:
// <= ~5e-5 output delta, validated R7/R8/R10 — absmax at 0.0039 floor.)
// ---------------------------------------------------------------------------
__global__ __launch_bounds__(256) void prep_kernel(
    const float* __restrict__ alpha, const float* __restrict__ th,
    const float* __restrict__ amb,
    unsigned short* __restrict__ Whi, unsigned short* __restrict__ Wlo,
    float* __restrict__ off)
{
    int mk = blockIdx.x * 256 + threadIdx.x;
    if (mk >= MK) return;
    float v[D_];
    float mx = -1e30f;
#pragma unroll
    for (int d = 0; d < D_; ++d) { v[d] = alpha[mk * D_ + d]; mx = fmaxf(mx, v[d]); }
    float sum = 0.f;
#pragma unroll
    for (int d = 0; d < D_; ++d) { v[d] = expf(v[d] - mx); sum += v[d]; }
    float pos = amb[mk * 2 + 0];
    float neg = amb[mk * 2 + 1];
    float s  = 1.0f / (pos - neg + EPS_DIV);
    float si = s / sum;
#pragma unroll
    for (int d = 0; d < D_; ++d) {
        float w = v[d] * si;
        unsigned short h = f2bf(w);
        Whi[mk * D_ + d] = h;
        Wlo[mk * D_ + d] = f2bf(w - bf2f(h));
    }
    off[mk] = (0.0f - th[mk] - neg) * s;
}

// ---------------------------------------------------------------------------
// Main: block-cooperative strip kernel with FULLY ROW-LINEAR stores.
// Compute phase (per wave, swapped operands — R8/R10-verified mapping):
//   acc f32x4 = 4 consecutive mk of one n-row -> one ds_write_b128 into the
//   block-shared stage [16 rows][512 f32], XOR-swizzled 16B chunks.
// Store phase (all 256 threads): 8 steps x {ds_read_b128, epilogue,
//   global_store_dwordx4}; each wave-instruction writes 1024 B CONTIGUOUS,
//   each row of the half-strip is one 2 KB run from one block (vs 8 scattered
//   512 B writers in R10). 4 waves share the same T rows (L1 temporal reuse).
// Half (col 0..511 vs 512..1023) is fixed per block (grid stride even), so W
// fragments + epilogue offsets stay register-hoisted.
// 3-MFMA hi/lo split keeps fp32-level accuracy (Tlo*Wlo term dropped).
// ---------------------------------------------------------------------------
__global__ __launch_bounds__(256, 4) void fern_mfma(
    const float* __restrict__ T,
    const unsigned short* __restrict__ Whi, const unsigned short* __restrict__ Wlo,
    const float* __restrict__ off, float* __restrict__ out)
{
    __shared__ float stage[ROWS][LDSF];         // 32 KB

    const int tid  = threadIdx.x;
    const int lane = tid & 63;
    const int wid  = tid >> 6;
    const int lc   = lane & 15;                 // A row (mk) / B col (n)
    const int lk   = lane >> 4;                 // k-group (8 contiguous k)
    const int half = blockIdx.x & 1;
    const int mkb  = half * HALF;
    const int mk0  = mkb + wid * 128;           // this wave's 128-col slice

    // ---- hoist W fragments (A operand, swapped) for this wave's 128 cols
    short8 wh[NT], wl[NT];
#pragma unroll
    for (int t = 0; t < NT; ++t) {
        long c = (long)(mk0 + t * 16 + lc);
        wh[t] = *(const short8*)(Whi + c * D_ + lk * 8);
        wl[t] = *(const short8*)(Wlo + c * D_ + lk * 8);
    }
    // ---- store-phase constants: thread covers cols mkb + 4*sc .. +3
    const int sc  = tid & 127;                  // 16B chunk within half-row
    const int sr0 = tid >> 7;                   // row parity (0/1)
    const f32x4 ofv = *(const f32x4*)(off + mkb + 4 * sc);

    // ---- grid-stride over (strip, half) tasks; task&1 == blockIdx&1 always
    for (int task = blockIdx.x; task < NTASK; task += NBLK) {
        const int n0 = (task >> 1) * ROWS;

        // T fragment (B operand): col n = n0+lc, k = lk*8 .. +7  (32 B of f32)
        const float* tp = T + (long)(n0 + lc) * D_ + lk * 8;
        float4 v0 = *(const float4*)tp;
        float4 v1 = *(const float4*)(tp + 4);
        float xs[8] = { v0.x, v0.y, v0.z, v0.w, v1.x, v1.y, v1.z, v1.w };
        short8 ah, al;
#pragma unroll
        for (int j = 0; j < 8; ++j) {
            unsigned short h = f2bf(xs[j]);
            ah[j] = (short)h;
            al[j] = (short)f2bf(xs[j] - bf2f(h));
        }

        // ---- compute 8 tiles; stage raw acc (1 ds_write_b128 per tile)
        // D[mk][n] swapped: n-row = lc, mk chunk = wid*32 + t*4 + lk
#pragma unroll
        for (int t = 0; t < NT; ++t) {
            f32x4 acc = { 0.f, 0.f, 0.f, 0.f };
            acc = __builtin_amdgcn_mfma_f32_16x16x32_bf16(wh[t], ah, acc, 0, 0, 0);
            acc = __builtin_amdgcn_mfma_f32_16x16x32_bf16(wh[t], al, acc, 0, 0, 0);
            acc = __builtin_amdgcn_mfma_f32_16x16x32_bf16(wl[t], ah, acc, 0, 0, 0);
            const int chunk = (wid * 32 + t * 4 + lk) ^ (lc & 7);   // XOR swizzle
            *(f32x4*)&stage[lc][chunk * 4] = acc;
        }
        __syncthreads();

        // ---- cooperative row-linear store: step s covers rows 2s, 2s+1;
        // each wave-instruction = 64 lanes x 16 B = 1024 B contiguous.
#pragma unroll
        for (int s = 0; s < 8; ++s) {
            const int r = 2 * s + sr0;
            const int k = sc ^ (r & 7);                              // un-swizzle
            f32x4 v = *(const f32x4*)&stage[r][k * 4];
            f32x4 rr;
#pragma unroll
            for (int j = 0; j < 4; ++j)
                rr[j] = fminf(fmaxf(v[j] + ofv[j], 0.f), 1.f);
            *(f32x4*)(out + (long)(n0 + r) * MK + mkb + 4 * sc) = rr;
        }
        __syncthreads();
    }
}

extern "C" void kernel_launch(void* const* d_in, const int* in_sizes, int n_in,
                              void* d_out, int out_size, void* d_ws, size_t ws_size,
                              hipStream_t stream)
{
    const float* T     = (const float*)d_in[0];
    const float* alpha = (const float*)d_in[1];
    const float* th    = (const float*)d_in[2];
    const float* amb   = (const float*)d_in[3];
    float* out = (float*)d_out;

    // ws layout: Whi[32768 u16] | Wlo[32768 u16] | off[1024 f32] = 135,168 B
    unsigned short* Whi = (unsigned short*)d_ws;
    unsigned short* Wlo = Whi + MK * D_;
    float* offp = (float*)(Wlo + MK * D_);

    prep_kernel<<<MK / 256, 256, 0, stream>>>(alpha, th, amb, Whi, Wlo, offp);
    fern_mfma<<<NBLK, 256, 0, stream>>>(T, Whi, Wlo, offp, out);
}